// Round 1
// baseline (301.508 us; speedup 1.0000x reference)
//
#include <hip/hip_runtime.h>
#include <math.h>

#define DIM  (1 << 20)       // 2^20 amplitudes
#define G4   (DIM / 4)       // 262144 float4 per batch row
#define NB   32              // batch
#define NQ   20              // qubits
#define NL   8               // layers
#define NACC 21              // 20 qubit sums + 1 total

// ---------------- Kernel 1: P[i] = prod_l noise[l][i] ----------------
__global__ __launch_bounds__(256) void qnn_prod(const float4* __restrict__ noise,
                                                float4* __restrict__ P) {
    int g = blockIdx.x * 256 + threadIdx.x;   // grid covers G4 exactly
    float4 p = noise[g];
#pragma unroll
    for (int l = 1; l < NL; ++l) {
        float4 n = noise[l * G4 + g];
        p.x *= n.x; p.y *= n.y; p.z *= n.z; p.w *= n.w;
    }
    P[g] = p;
}

// ---------------- Kernel 2: per-batch masked sums ----------------
// Q[b][q]  (q<20) = sum_{i: bit q of i set} (amps0[b,i]*P[i])^2
// Q[b][20]        = sum_i (amps0[b,i]*P[i])^2
template <int USE_P>
__global__ __launch_bounds__(256) void qnn_accum(const float4* __restrict__ amps,
                                                 const float4* __restrict__ P,
                                                 const float4* __restrict__ noise,
                                                 float* __restrict__ Q) {
    const int tid   = threadIdx.x;      // [0,256)
    const int chunk = blockIdx.x;       // [0,32)  -> i bits 15..19
    const int b     = blockIdx.y;       // [0,32)
    const float4* __restrict__ arow = amps + (size_t)b * G4;

    float total = 0.0f, q0 = 0.0f, q1 = 0.0f;
    float acc[7] = {0.f, 0.f, 0.f, 0.f, 0.f, 0.f, 0.f};

#pragma unroll 4
    for (int iter = 0; iter < 32; ++iter) {
        const int g = chunk * 8192 + iter * 256 + tid;   // float4 index in [0, G4)
        float4 a = arow[g];
        float4 p;
        if (USE_P) {
            p = P[g];
        } else {
            p = noise[g];
#pragma unroll
            for (int l = 1; l < NL; ++l) {
                float4 n = noise[l * G4 + g];
                p.x *= n.x; p.y *= n.y; p.z *= n.z; p.w *= n.w;
            }
        }
        float w0 = a.x * p.x; w0 *= w0;
        float w1 = a.y * p.y; w1 *= w1;
        float w2 = a.z * p.z; w2 *= w2;
        float w3 = a.w * p.w; w3 *= w3;
        const float s = (w0 + w1) + (w2 + w3);
        total += s;
        q0 += w1 + w3;                 // i bit 0 set  (j = 1,3)
        q1 += w2 + w3;                 // i bit 1 set  (j = 2,3)
        const int hl = iter * 4 + (tid >> 6);   // i bits 8..14 (wave-uniform)
#pragma unroll
        for (int k = 0; k < 7; ++k)
            acc[k] += ((hl >> k) & 1) ? s : 0.0f;
    }

    // Expand per-thread partials to the full 21 accumulators.
    float v[NACC];
    v[0] = q0;
    v[1] = q1;
#pragma unroll
    for (int j = 0; j < 6; ++j)        // i bits 2..7 <- tid bits 0..5 (thread-const)
        v[2 + j] = ((tid >> j) & 1) ? total : 0.0f;
#pragma unroll
    for (int k = 0; k < 7; ++k)        // i bits 8..14
        v[8 + k] = acc[k];
#pragma unroll
    for (int m = 0; m < 5; ++m)        // i bits 15..19 <- chunk bits (block-const)
        v[15 + m] = ((chunk >> m) & 1) ? total : 0.0f;
    v[20] = total;

    // Wave (64-lane) tree reduce, then one atomic per wave per accumulator.
#pragma unroll
    for (int off = 32; off >= 1; off >>= 1) {
#pragma unroll
        for (int t = 0; t < NACC; ++t)
            v[t] += __shfl_down(v[t], off, 64);
    }
    if ((tid & 63) == 0) {
#pragma unroll
        for (int t = 0; t < NACC; ++t)
            atomicAdd(&Q[b * NACC + t], v[t]);
    }
}

// ---------------- Kernel 3: qubit_probs @ Wi + bi, tanh ----------------
__global__ void qnn_final(const float* __restrict__ Q,
                          const float* __restrict__ Wi,
                          const float* __restrict__ bi,
                          float* __restrict__ out) {
    const int j = threadIdx.x;
    if (j >= NB * NQ) return;
    const int b = j / NQ;
    const int n = j % NQ;
    const float* __restrict__ qrow = Q + b * NACC;
    const float inv = 1.0f / qrow[20];
    float acc = bi[n];
#pragma unroll
    for (int q = 0; q < NQ; ++q)
        acc += (qrow[q] * inv) * Wi[q * NQ + n];
    out[b * NQ + n] = tanhf(acc);
}

extern "C" void kernel_launch(void* const* d_in, const int* in_sizes, int n_in,
                              void* d_out, int out_size, void* d_ws, size_t ws_size,
                              hipStream_t stream) {
    // setup_inputs order: x, W1, b1, W2, b2, W3, b3, amps0, cnot_noise, Wi, bi
    const float* amps0 = (const float*)d_in[7];
    const float* noise = (const float*)d_in[8];
    const float* Wi    = (const float*)d_in[9];
    const float* bi    = (const float*)d_in[10];
    float* out = (float*)d_out;

    float* Q = (float*)d_ws;                          // 32*21 floats at offset 0
    const size_t P_OFF = 4096;
    float* P = (float*)((char*)d_ws + P_OFF);
    const bool useP = ws_size >= P_OFF + (size_t)DIM * sizeof(float);

    hipMemsetAsync(d_ws, 0, NB * NACC * sizeof(float), stream);

    if (useP) {
        qnn_prod<<<G4 / 256, 256, 0, stream>>>((const float4*)noise, (float4*)P);
        qnn_accum<1><<<dim3(32, 32), 256, 0, stream>>>(
            (const float4*)amps0, (const float4*)P, nullptr, Q);
    } else {
        qnn_accum<0><<<dim3(32, 32), 256, 0, stream>>>(
            (const float4*)amps0, nullptr, (const float4*)noise, Q);
    }
    qnn_final<<<1, 640, 0, stream>>>(Q, Wi, bi, out);
}

// Round 2
// 237.620 us; speedup vs baseline: 1.2689x; 1.2689x over previous
//
#include <hip/hip_runtime.h>
#include <math.h>

#define DIM  (1 << 20)       // 2^20 amplitudes
#define G4   (DIM / 4)       // 262144 float4 per batch row
#define NB   32              // batch
#define NQ   20              // qubits
#define NL   8               // layers
#define NACC 21              // 20 qubit sums + 1 total
#define NCHUNK 32            // chunks per batch row (i bits 15..19)

// ---------------- Kernel 1: P[i] = prod_l noise[l][i] ----------------
__global__ __launch_bounds__(256) void qnn_prod(const float4* __restrict__ noise,
                                                float4* __restrict__ P) {
    int g = blockIdx.x * 256 + threadIdx.x;   // grid covers G4 exactly
    float4 p = noise[g];
#pragma unroll
    for (int l = 1; l < NL; ++l) {
        float4 n = noise[l * G4 + g];
        p.x *= n.x; p.y *= n.y; p.z *= n.z; p.w *= n.w;
    }
    P[g] = p;
}

// ---------------- Kernel 2: per-batch masked partial sums ----------------
// partial[b][chunk][q] (q<20) = sum over this chunk of (amps0[b,i]*P[i])^2 where bit q of i set
// partial[b][chunk][20]       = chunk total
template <int USE_P>
__global__ __launch_bounds__(256) void qnn_accum(const float4* __restrict__ amps,
                                                 const float4* __restrict__ P,
                                                 const float4* __restrict__ noise,
                                                 float* __restrict__ partial) {
    const int tid   = threadIdx.x;      // [0,256)
    const int chunk = blockIdx.x;       // [0,32)  -> i bits 15..19
    const int b     = blockIdx.y;       // [0,32)
    const float4* __restrict__ arow = amps + (size_t)b * G4;

    float total = 0.0f, q0 = 0.0f, q1 = 0.0f;
    float acc[7] = {0.f, 0.f, 0.f, 0.f, 0.f, 0.f, 0.f};

#pragma unroll 4
    for (int iter = 0; iter < 32; ++iter) {
        const int g = chunk * 8192 + iter * 256 + tid;   // float4 index in [0, G4)
        float4 a = arow[g];
        float4 p;
        if (USE_P) {
            p = P[g];
        } else {
            p = noise[g];
#pragma unroll
            for (int l = 1; l < NL; ++l) {
                float4 n = noise[l * G4 + g];
                p.x *= n.x; p.y *= n.y; p.z *= n.z; p.w *= n.w;
            }
        }
        float w0 = a.x * p.x; w0 *= w0;
        float w1 = a.y * p.y; w1 *= w1;
        float w2 = a.z * p.z; w2 *= w2;
        float w3 = a.w * p.w; w3 *= w3;
        const float s = (w0 + w1) + (w2 + w3);
        total += s;
        q0 += w1 + w3;                 // i bit 0 set  (j = 1,3)
        q1 += w2 + w3;                 // i bit 1 set  (j = 2,3)
        const int hl = iter * 4 + (tid >> 6);   // i bits 8..14 (wave-uniform)
#pragma unroll
        for (int k = 0; k < 7; ++k)
            acc[k] += ((hl >> k) & 1) ? s : 0.0f;
    }

    // Expand per-thread partials to the full 21 accumulators.
    float v[NACC];
    v[0] = q0;
    v[1] = q1;
#pragma unroll
    for (int j = 0; j < 6; ++j)        // i bits 2..7 <- lane bits 0..5 (thread-const)
        v[2 + j] = ((tid >> j) & 1) ? total : 0.0f;
#pragma unroll
    for (int k = 0; k < 7; ++k)        // i bits 8..14
        v[8 + k] = acc[k];
#pragma unroll
    for (int m = 0; m < 5; ++m)        // i bits 15..19 <- chunk bits (block-const)
        v[15 + m] = ((chunk >> m) & 1) ? total : 0.0f;
    v[20] = total;

    // Wave (64-lane) tree reduce.
#pragma unroll
    for (int off = 32; off >= 1; off >>= 1) {
#pragma unroll
        for (int t = 0; t < NACC; ++t)
            v[t] += __shfl_down(v[t], off, 64);
    }

    // Cross-wave combine in LDS, then ONE plain 21-float store per block.
    __shared__ float lred[4][NACC + 1];
    const int wave = tid >> 6;
    if ((tid & 63) == 0) {
#pragma unroll
        for (int t = 0; t < NACC; ++t)
            lred[wave][t] = v[t];
    }
    __syncthreads();
    if (tid < NACC) {
        float s = (lred[0][tid] + lred[1][tid]) + (lred[2][tid] + lred[3][tid]);
        partial[((size_t)b * NCHUNK + chunk) * NACC + tid] = s;
    }
}

// ---------------- Kernel 3: reduce chunks, qubit_probs @ Wi + bi, tanh ----------------
__global__ __launch_bounds__(64) void qnn_final(const float* __restrict__ partial,
                                                const float* __restrict__ Wi,
                                                const float* __restrict__ bi,
                                                float* __restrict__ out) {
    const int b = blockIdx.x;
    const int t = threadIdx.x;       // 64 threads
    __shared__ float s[NACC];
    if (t < NACC) {
        const float* __restrict__ p = partial + (size_t)b * NCHUNK * NACC + t;
        float acc = 0.0f;
#pragma unroll
        for (int c = 0; c < NCHUNK; ++c)
            acc += p[c * NACC];
        s[t] = acc;
    }
    __syncthreads();
    if (t < NQ) {
        const float inv = 1.0f / s[20];
        float acc = bi[t];
#pragma unroll
        for (int q = 0; q < NQ; ++q)
            acc += (s[q] * inv) * Wi[q * NQ + t];
        out[b * NQ + t] = tanhf(acc);
    }
}

extern "C" void kernel_launch(void* const* d_in, const int* in_sizes, int n_in,
                              void* d_out, int out_size, void* d_ws, size_t ws_size,
                              hipStream_t stream) {
    // setup_inputs order: x, W1, b1, W2, b2, W3, b3, amps0, cnot_noise, Wi, bi
    const float* amps0 = (const float*)d_in[7];
    const float* noise = (const float*)d_in[8];
    const float* Wi    = (const float*)d_in[9];
    const float* bi    = (const float*)d_in[10];
    float* out = (float*)d_out;

    // ws layout: [0, 128KB) partials (needs 84KB), [128KB, 128KB+4MB) P
    float* partial = (float*)d_ws;
    const size_t P_OFF = 128 * 1024;
    float* P = (float*)((char*)d_ws + P_OFF);
    const bool useP = ws_size >= P_OFF + (size_t)DIM * sizeof(float);

    if (useP) {
        qnn_prod<<<G4 / 256, 256, 0, stream>>>((const float4*)noise, (float4*)P);
        qnn_accum<1><<<dim3(NCHUNK, NB), 256, 0, stream>>>(
            (const float4*)amps0, (const float4*)P, nullptr, partial);
    } else {
        qnn_accum<0><<<dim3(NCHUNK, NB), 256, 0, stream>>>(
            (const float4*)amps0, nullptr, (const float4*)noise, partial);
    }
    qnn_final<<<NB, 64, 0, stream>>>(partial, Wi, bi, out);
}

// Round 3
// 229.200 us; speedup vs baseline: 1.3155x; 1.0367x over previous
//
#include <hip/hip_runtime.h>
#include <math.h>

#define DIM  (1 << 20)       // 2^20 amplitudes
#define G4   (DIM / 4)       // 262144 float4 per batch row
#define NB   32              // batch
#define NQ   20              // qubits
#define NL   8               // layers
#define NACC 21              // 20 qubit sums + 1 total
#define NCHUNK 32            // chunks per batch row (i bits 15..19)

typedef float f4 __attribute__((ext_vector_type(4)));

// ---------------- Kernel 1: P[i] = prod_l noise[l][i] ----------------
__global__ __launch_bounds__(256) void qnn_prod(const f4* __restrict__ noise,
                                                f4* __restrict__ P) {
    int g = blockIdx.x * 256 + threadIdx.x;   // grid covers G4 exactly
    f4 p = noise[g];
#pragma unroll
    for (int l = 1; l < NL; ++l) {
        f4 n = noise[l * G4 + g];
        p *= n;
    }
    P[g] = p;
}

// ---------------- Kernel 2: per-batch masked partial sums ----------------
// Element index decomposition: i = j + 4*tid + 1024*iter + 32768*chunk
//   i bits 0..1  <- j    (float4 lane)        -> q0,q1 accumulators
//   i bits 2..9  <- tid  (loop-invariant!)    -> masked copy of `total` at the end
//   i bits 10..14<- iter (compile-time under unroll) -> siter[5]
//   i bits 15..19<- chunk (block-constant)    -> masked copy of `total` at the end
__global__ __launch_bounds__(256) void qnn_accum(const f4* __restrict__ amps,
                                                 const f4* __restrict__ P,
                                                 float* __restrict__ partial) {
    const int tid   = threadIdx.x;      // [0,256)
    const int chunk = blockIdx.x;       // [0,32)
    const int b     = blockIdx.y;       // [0,32)
    const f4* __restrict__ arow = amps + (size_t)b * G4 + chunk * 8192;
    const f4* __restrict__ prow = P + chunk * 8192;

    float total = 0.0f, q0 = 0.0f, q1 = 0.0f;
    float siter[5] = {0.f, 0.f, 0.f, 0.f, 0.f};

    for (int o = 0; o < 4; ++o) {       // iter bits 3..4
        float s8 = 0.0f;
#pragma unroll
        for (int k = 0; k < 8; ++k) {   // iter bits 0..2 (compile-time)
            const int g = (o * 8 + k) * 256 + tid;
            f4 a = __builtin_nontemporal_load(arow + g);
            f4 p = prow[g];
            float w0 = a.x * p.x; w0 *= w0;
            float w1 = a.y * p.y; w1 *= w1;
            float w2 = a.z * p.z; w2 *= w2;
            float w3 = a.w * p.w; w3 *= w3;
            const float w01 = w0 + w1, w23 = w2 + w3;
            const float s = w01 + w23;
            s8 += s;
            q0 += w1 + w3;              // i bit 0 set (j = 1,3)
            q1 += w23;                  // i bit 1 set (j = 2,3)
            if (k & 1) siter[0] += s;   // compile-time folds
            if (k & 2) siter[1] += s;
            if (k & 4) siter[2] += s;
        }
        total += s8;
        siter[3] += (o & 1) ? s8 : 0.0f;   // iter bit 3
        siter[4] += (o & 2) ? s8 : 0.0f;   // iter bit 4
    }

    // Expand to the full 21 accumulators.
    float v[NACC];
    v[0] = q0;
    v[1] = q1;
#pragma unroll
    for (int j = 0; j < 8; ++j)        // i bits 2..9 <- tid bits 0..7 (loop-invariant)
        v[2 + j] = ((tid >> j) & 1) ? total : 0.0f;
#pragma unroll
    for (int k = 0; k < 5; ++k)        // i bits 10..14
        v[10 + k] = siter[k];
#pragma unroll
    for (int m = 0; m < 5; ++m)        // i bits 15..19 <- chunk bits (block-const)
        v[15 + m] = ((chunk >> m) & 1) ? total : 0.0f;
    v[20] = total;

    // Wave (64-lane) butterfly reduce.
#pragma unroll
    for (int off = 32; off >= 1; off >>= 1) {
#pragma unroll
        for (int t = 0; t < NACC; ++t)
            v[t] += __shfl_down(v[t], off, 64);
    }

    // Cross-wave combine in LDS, then ONE plain 21-float store per block.
    __shared__ float lred[4][NACC + 1];
    const int wave = tid >> 6;
    if ((tid & 63) == 0) {
#pragma unroll
        for (int t = 0; t < NACC; ++t)
            lred[wave][t] = v[t];
    }
    __syncthreads();
    if (tid < NACC) {
        float s = (lred[0][tid] + lred[1][tid]) + (lred[2][tid] + lred[3][tid]);
        partial[((size_t)b * NCHUNK + chunk) * NACC + tid] = s;
    }
}

// ---------------- Kernel 3: reduce chunks, qubit_probs @ Wi + bi, tanh ----------------
__global__ __launch_bounds__(64) void qnn_final(const float* __restrict__ partial,
                                                const float* __restrict__ Wi,
                                                const float* __restrict__ bi,
                                                float* __restrict__ out) {
    const int b = blockIdx.x;
    const int t = threadIdx.x;       // 64 threads
    __shared__ float s[NACC];
    if (t < NACC) {
        const float* __restrict__ p = partial + (size_t)b * NCHUNK * NACC + t;
        float acc = 0.0f;
#pragma unroll
        for (int c = 0; c < NCHUNK; ++c)
            acc += p[c * NACC];
        s[t] = acc;
    }
    __syncthreads();
    if (t < NQ) {
        const float inv = 1.0f / s[20];
        float acc = bi[t];
#pragma unroll
        for (int q = 0; q < NQ; ++q)
            acc += (s[q] * inv) * Wi[q * NQ + t];
        out[b * NQ + t] = tanhf(acc);
    }
}

extern "C" void kernel_launch(void* const* d_in, const int* in_sizes, int n_in,
                              void* d_out, int out_size, void* d_ws, size_t ws_size,
                              hipStream_t stream) {
    // setup_inputs order: x, W1, b1, W2, b2, W3, b3, amps0, cnot_noise, Wi, bi
    const float* amps0 = (const float*)d_in[7];
    const float* noise = (const float*)d_in[8];
    const float* Wi    = (const float*)d_in[9];
    const float* bi    = (const float*)d_in[10];
    float* out = (float*)d_out;

    // ws layout: [0, 128KB) partials (needs 84KB), [128KB, 128KB+4MB) P
    float* partial = (float*)d_ws;
    const size_t P_OFF = 128 * 1024;
    f4* P = (f4*)((char*)d_ws + P_OFF);

    qnn_prod<<<G4 / 256, 256, 0, stream>>>((const f4*)noise, P);
    qnn_accum<<<dim3(NCHUNK, NB), 256, 0, stream>>>(
        (const f4*)amps0, (const f4*)P, partial);
    qnn_final<<<NB, 64, 0, stream>>>(partial, Wi, bi, out);
}